// Round 16
// baseline (3074.847 us; speedup 1.0000x reference)
//
#include <hip/hip_runtime.h>
#include <hip/hip_bf16.h>
#include <math.h>

#define TT   512
#define CC   768
#define HH   12
#define HSZ  64
#define LL   12
#define C4   3072
#define BTOT 2048   // B*T
#define NQKV 2304   // 3*C
#define NX   ((long)BTOT * CC)

typedef __attribute__((ext_vector_type(8))) short short8;
typedef __attribute__((ext_vector_type(4))) float f32x4;

__device__ __forceinline__ unsigned short f2b_bits(float f) {
    unsigned u = __float_as_uint(f);
    return (unsigned short)((u + 0x7fffu + ((u >> 16) & 1u)) >> 16);
}
__device__ __forceinline__ float b2f(unsigned short b) {
    return __uint_as_float((unsigned)b << 16);
}
// tanh-GELU, overflow-safe; |err| vs exact-erf GELU < 3e-3 (below bf16 step)
__device__ __forceinline__ float gelu_t(float v) {
    float u = 0.7978845608f * fmaf(0.044715f * v, v * v, v);
    float th = 1.f - 2.f / (1.f + __expf(2.f * u));
    return 0.5f * v * (1.f + th);
}

// async global->LDS, 16B per lane; LDS dest is wave-uniform base + lane*16B
__device__ __forceinline__ void gl_lds16(const void* g, void* l) {
    __builtin_amdgcn_global_load_lds(
        (const __attribute__((address_space(1))) unsigned int*)g,
        (__attribute__((address_space(3))) unsigned int*)l,
        16, 0, 0);
}

// ------------------------------------------------- embedding + layer-0 LN1
__global__ __launch_bounds__(256) void embed_ln(const int* __restrict__ idx,
    const float* __restrict__ tok, const float* __restrict__ pos,
    const float* __restrict__ g, const float* __restrict__ b,
    float* __restrict__ x, __hip_bfloat16* __restrict__ y)
{
    int r = blockIdx.x, tid = threadIdx.x;
    int t = r & (TT - 1);
    long id = idx[r];
    const float* te = tok + id * (long)CC;
    const float* pe = pos + (long)t * CC;
    float* xr = x + (long)r * CC;
    float v[3];
#pragma unroll
    for (int i = 0; i < 3; ++i) {
        int c = tid + i * 256;
        v[i] = te[c] + pe[c];
        xr[c] = v[i];
    }
    float s  = v[0] + v[1] + v[2];
    float sq = v[0]*v[0] + v[1]*v[1] + v[2]*v[2];
#pragma unroll
    for (int off = 32; off > 0; off >>= 1) {
        s  += __shfl_down(s, off);
        sq += __shfl_down(sq, off);
    }
    __shared__ float ss[4], ssq[4];
    int w = tid >> 6;
    if ((tid & 63) == 0) { ss[w] = s; ssq[w] = sq; }
    __syncthreads();
    s  = ss[0] + ss[1] + ss[2] + ss[3];
    sq = ssq[0] + ssq[1] + ssq[2] + ssq[3];
    float mean = s * (1.0f / CC);
    float var  = sq * (1.0f / CC) - mean * mean;
    float rs   = rsqrtf(var + 1e-5f);
    __hip_bfloat16* yr = y + (long)r * CC;
#pragma unroll
    for (int i = 0; i < 3; ++i) {
        int c = tid + i * 256;
        yr[c] = __float2bfloat16((v[i] - mean) * rs * g[c] + b[c]);
    }
}

// ------------------------------------------------- weight convert/transpose
// src fp32 [R][D] -> dst bf16 [D][R]; 64x64 tiles; grid (D/64, R/64, L)
__global__ __launch_bounds__(256) void cvtT_k(const float* __restrict__ src,
    __hip_bfloat16* __restrict__ dst, int R, int D, long sSrc, long sDst)
{
    src += (long)blockIdx.z * sSrc;
    dst += (long)blockIdx.z * sDst;
    __shared__ float t[64][65];
    int d0 = blockIdx.x * 64, r0 = blockIdx.y * 64;
    int tid = threadIdx.x;
#pragma unroll
    for (int i = 0; i < 4; ++i) {
        int flat = tid + i * 256;
        int r = flat >> 4, c4 = (flat & 15) * 4;
        float4 v = *(const float4*)&src[(long)(r0 + r) * D + d0 + c4];
        t[r][c4 + 0] = v.x; t[r][c4 + 1] = v.y;
        t[r][c4 + 2] = v.z; t[r][c4 + 3] = v.w;
    }
    __syncthreads();
#pragma unroll
    for (int i = 0; i < 4; ++i) {
        int flat = tid + i * 256;
        int n = flat >> 4, kq = (flat & 15) * 4;
        ushort4 o;
        o.x = f2b_bits(t[kq + 0][n]); o.y = f2b_bits(t[kq + 1][n]);
        o.z = f2b_bits(t[kq + 2][n]); o.w = f2b_bits(t[kq + 3][n]);
        *(ushort4*)&dst[(long)(d0 + n) * R + r0 + kq] = o;
    }
}

// Wq/Wk/Wv [L][h][768][64] -> qkvT_all [L][2304][768]; grid (12, 36, L)
__global__ __launch_bounds__(256) void cvt_qkvT(const float* __restrict__ Wq,
    const float* __restrict__ Wk, const float* __restrict__ Wv,
    __hip_bfloat16* __restrict__ out)
{
    int c0 = blockIdx.x * 64;
    int g  = blockIdx.y;
    int l  = blockIdx.z;
    int which = g / 12, h = g % 12;
    const long wAtt = (long)HH * CC * HSZ;
    const float* src = (which == 0 ? Wq : which == 1 ? Wk : Wv)
                       + l * wAtt + (long)h * CC * HSZ;   // [768][64]
    __hip_bfloat16* dst = out + (long)l * NQKV * CC + (long)(which * CC + h * HSZ) * CC;
    __shared__ float t[64][65];
    int tid = threadIdx.x;
#pragma unroll
    for (int i = 0; i < 4; ++i) {
        int flat = tid + i * 256;
        int r = flat >> 4, c4 = (flat & 15) * 4;
        float4 v = *(const float4*)&src[(long)(c0 + r) * HSZ + c4];
        t[r][c4 + 0] = v.x; t[r][c4 + 1] = v.y;
        t[r][c4 + 2] = v.z; t[r][c4 + 3] = v.w;
    }
    __syncthreads();
#pragma unroll
    for (int i = 0; i < 4; ++i) {
        int flat = tid + i * 256;
        int n = flat >> 4, kq = (flat & 15) * 4;
        ushort4 o;
        o.x = f2b_bits(t[kq + 0][n]); o.y = f2b_bits(t[kq + 1][n]);
        o.z = f2b_bits(t[kq + 2][n]); o.w = f2b_bits(t[kq + 3][n]);
        *(ushort4*)&dst[(long)n * CC + c0 + kq] = o;
    }
}

// ---------------------------------------------------------------- bf16 MFMA GEMM (64x128)
// Depth-4 pipeline, counted vmcnt, T1 XCD swizzle, T2 bank rotation.
// EPI 1: QKV (cols<1536 -> Cb, cols>=1536 -> Vt transposed);
// EPI 2: +bias tanh-GELU -> bf16;
// EPI 6: split-K bf16 partial -> Cb + sk*NX, then last-block-per-slab fused
//        reduce: xR += sum(partials)+bias, xn(=Vt) = LN(xR; gln,bln).
template <int EPI>
__global__ __launch_bounds__(256, 3) void gemm_bf16(
    const __hip_bfloat16* __restrict__ A,
    const __hip_bfloat16* __restrict__ BT,
    __hip_bfloat16* __restrict__ Cb, float* __restrict__ xR,
    const float* __restrict__ bias, __hip_bfloat16* __restrict__ Vt,
    const float* __restrict__ gln, const float* __restrict__ bln,
    int* __restrict__ cnt,
    int K, int lda, int ldb, int ldc)
{
    __shared__ short Asm[4][64 * 32];
    __shared__ short Bsm[4][128 * 32];
    const int tid  = threadIdx.x;
    const int lane = tid & 63;
    const int wid  = tid >> 6;
    const int wm = wid >> 1, wn = wid & 1;

    const int gx = gridDim.x;
    const int slice = gx * gridDim.y;            // divisible by 8
    int flat = blockIdx.y * gx + blockIdx.x;
    int swz  = (flat & 7) * (slice >> 3) + (flat >> 3);
    const int row0 = (swz / gx) * 64, col0 = (swz % gx) * 128;
    const int sk = (EPI == 6) ? blockIdx.z : 0;

    const int gr = tid >> 2;               // staging row 0..63
    const int cb = ((tid & 3) + (tid >> 3)) & 3;   // T2 source rotation
    const int gk = cb * 8;                 // k offset in shorts
    const __hip_bfloat16* Ap = A  + (long)(row0 + gr) * lda + sk * K + gk;
    const __hip_bfloat16* Bp = BT + (long)(col0 + gr) * ldb + sk * K + gk;
    const int lofs = wid * 512;            // per-wave LDS segment (shorts)

    f32x4 acc[2][4] = {};
    const int fr = lane & 15, g = lane >> 4;

    int offA[2], offB[4];
#pragma unroll
    for (int m = 0; m < 2; ++m) {
        int row = wm * 32 + m * 16 + fr;
        offA[m] = row * 32 + (((g - (row >> 1)) & 3) * 8);
    }
#pragma unroll
    for (int n = 0; n < 4; ++n) {
        int row = wn * 64 + n * 16 + fr;
        offB[n] = row * 32 + (((g - (row >> 1)) & 3) * 8);
    }

#define STAGE(buf)                                                          \
    do {                                                                    \
        gl_lds16(Ap, &Asm[buf][lofs]);                                      \
        gl_lds16(Bp, &Bsm[buf][lofs]);                                      \
        gl_lds16(Bp + (long)64 * ldb, &Bsm[buf][lofs + 64 * 32]);           \
        Ap += 32; Bp += 32;                                                 \
    } while (0)

    STAGE(0); STAGE(1); STAGE(2);

    const int nt = K >> 5;                 // >= 3
    for (int t = 0; t < nt; ++t) {
        if (t < nt - 2)       asm volatile("s_waitcnt vmcnt(6)" ::: "memory");
        else if (t == nt - 2) asm volatile("s_waitcnt vmcnt(3)" ::: "memory");
        else                  asm volatile("s_waitcnt vmcnt(0)" ::: "memory");
        __builtin_amdgcn_s_barrier();
        __builtin_amdgcn_sched_barrier(0);
        if (t + 3 < nt) STAGE((t + 3) & 3);

        const int cur = t & 3;
        short8 af[2], bf[4];
#pragma unroll
        for (int m = 0; m < 2; ++m)
            af[m] = *(const short8*)&Asm[cur][offA[m]];
#pragma unroll
        for (int n = 0; n < 4; ++n)
            bf[n] = *(const short8*)&Bsm[cur][offB[n]];
#pragma unroll
        for (int m = 0; m < 2; ++m)
#pragma unroll
            for (int n = 0; n < 4; ++n)
                acc[m][n] = __builtin_amdgcn_mfma_f32_16x16x32_bf16(
                    af[m], bf[n], acc[m][n], 0, 0, 0);
    }
#undef STAGE

    const int fq = lane >> 4;
#pragma unroll
    for (int m = 0; m < 2; ++m) {
        int rbase = row0 + wm * 32 + m * 16 + fq * 4;
#pragma unroll
        for (int n = 0; n < 4; ++n) {
            int col = col0 + wn * 64 + n * 16 + fr;
            if (EPI == 1 && col >= 1536) {
                int hd = col - 1536;
                int b = rbase >> 9, t = rbase & (TT - 1);
                ushort4 o;
                o.x = f2b_bits(acc[m][n][0]); o.y = f2b_bits(acc[m][n][1]);
                o.z = f2b_bits(acc[m][n][2]); o.w = f2b_bits(acc[m][n][3]);
                *(ushort4*)&Vt[((long)(b * HH + (hd >> 6)) * HSZ + (hd & 63)) * TT + t] = o;
                continue;
            }
            float bv = (EPI == 2) ? bias[col] : 0.f;
#pragma unroll
            for (int j = 0; j < 4; ++j) {
                long row = rbase + j;
                float v = acc[m][n][j];
                if (EPI == 1) {
                    Cb[row * ldc + col] = __float2bfloat16(v);
                } else if (EPI == 2) {
                    Cb[row * ldc + col] = __float2bfloat16(gelu_t(v + bv));
                } else { // EPI == 6: bf16 partial
                    Cb[(long)sk * NX + row * ldc + col] = __float2bfloat16(v);
                }
            }
        }
    }

    if (EPI != 6) return;

    // ---- last-block-per-slab fused reduce + residual + LN ----
    __shared__ int isLast;
    __syncthreads();                       // all partial stores drained (vmcnt 0)
    if (tid == 0) {
        __threadfence();                   // release: write back this XCD's L2
        const int slab = row0 >> 6;
        const int nC = gx * gridDim.z;     // contributors per slab (24)
        int old = __hip_atomic_fetch_add(&cnt[slab], 1,
                      __ATOMIC_ACQ_REL, __HIP_MEMORY_SCOPE_AGENT);
        int last = (old == nC - 1);
        if (last)
            __hip_atomic_store(&cnt[slab], 0,
                __ATOMIC_RELAXED, __HIP_MEMORY_SCOPE_AGENT);
        isLast = last;
    }
    __syncthreads();
    if (!isLast) return;
    __threadfence();                       // acquire: invalidate stale cache

    const unsigned short* pb = (const unsigned short*)Cb;
    const int w4 = tid >> 6;               // wave 0..3 handles 16 rows each
#pragma unroll 1
    for (int rr = 0; rr < 16; ++rr) {
        int r = (row0) + w4 * 16 + rr;
        float* xr = xR + (long)r * CC;
        const unsigned short* pr = pb + (long)r * CC;
        float vv[12];
        float s = 0.f, sq = 0.f;
#pragma unroll
        for (int i = 0; i < 12; ++i) {
            int c = lane + i * 64;
            float t = xr[c] + bias[c];
            t += b2f(pr[c]);
            t += b2f(pr[c + 1 * NX]);
            t += b2f(pr[c + 2 * NX]);
            t += b2f(pr[c + 3 * NX]);
            xr[c] = t;
            vv[i] = t;
            s += t; sq += t * t;
        }
#pragma unroll
        for (int off = 32; off > 0; off >>= 1) {
            s  += __shfl_xor(s, off);
            sq += __shfl_xor(sq, off);
        }
        float mean = s * (1.0f / CC);
        float var  = sq * (1.0f / CC) - mean * mean;
        float rs   = rsqrtf(var + 1e-5f);
        __hip_bfloat16* yr = Vt + (long)r * CC;   // Vt = xn output for EPI6
#pragma unroll
        for (int i = 0; i < 12; ++i) {
            int c = lane + i * 64;
            yr[c] = __float2bfloat16((vv[i] - mean) * rs * gln[c] + bln[c]);
        }
    }
}

// ---------------------------------------------------------------- MFMA flash attention
// QBLK=32: one wave handles 32 queries (halves A/B), sharing K-register chunks
// and V loads. One wave per block, NO __syncthreads. P/corr double-buffered by
// chunk parity. T1 XCD swizzle (768 blocks).
__global__ __launch_bounds__(64) void attn_mfma(
    const __hip_bfloat16* __restrict__ qkv,
    const __hip_bfloat16* __restrict__ vT,
    __hip_bfloat16* __restrict__ o)
{
    int flat = blockIdx.x + 16 * (blockIdx.y + 12 * blockIdx.z);
    int swz  = (flat & 7) * 96 + (flat >> 3);      // 768 blocks, 8 XCDs
    const int qt = swz & 15;
    const int h  = (swz >> 4) % 12;
    const int b  = swz / 192;
    const int lane = threadIdx.x;
    const int t0 = qt * 32;
    const int fr = lane & 15, g = lane >> 4;

    __shared__ unsigned short P_lds[2][32 * 40];
    __shared__ float corr_lds[2][32], l_lds[32];

    const long qbaseA = ((long)(b * TT + t0 + fr)) * NQKV + h * HSZ + g * 8;
    const long qbaseB = qbaseA + (long)16 * NQKV;
    short8 qfA0 = *(const short8*)(qkv + qbaseA);
    short8 qfA1 = *(const short8*)(qkv + qbaseA + 32);
    short8 qfB0 = *(const short8*)(qkv + qbaseB);
    short8 qfB1 = *(const short8*)(qkv + qbaseB + 32);

    f32x4 oaccA[4] = {}, oaccB[4] = {};
    float mA = -3.0e38f, lA = 0.f, mB = -3.0e38f, lB = 0.f;
    const int t_laneA = t0 + fr;
    const int t_laneB = t0 + 16 + fr;
    const int smax = t0 + 31;
    const long kcol = CC + h * HSZ + g * 8;
    const long vrow = (((long)(b * HH + h) * HSZ) + fr) * TT + g * 8;

    short8 ka0, ka1, ka2, ka3;
    {
        long kb0 = ((long)(b * TT + fr)) * NQKV + kcol;
        long kb1 = ((long)(b * TT + 16 + fr)) * NQKV + kcol;
        ka0 = *(const short8*)(qkv + kb0);
        ka1 = *(const short8*)(qkv + kb0 + 32);
        ka2 = *(const short8*)(qkv + kb1);
        ka3 = *(const short8*)(qkv + kb1 + 32);
    }

    for (int s0 = 0; s0 <= smax; s0 += 32) {
        const int pc = (s0 >> 5) & 1;
        f32x4 stA0 = {}, stA1 = {}, stB0 = {}, stB1 = {};
        stA0 = __builtin_amdgcn_mfma_f32_16x16x32_bf16(ka0, qfA0, stA0, 0, 0, 0);
        stA0 = __builtin_amdgcn_mfma_f32_16x16x32_bf16(ka1, qfA1, stA0, 0, 0, 0);
        stA1 = __builtin_amdgcn_mfma_f32_16x16x32_bf16(ka2, qfA0, stA1, 0, 0, 0);
        stA1 = __builtin_amdgcn_mfma_f32_16x16x32_bf16(ka3, qfA1, stA1, 0, 0, 0);
        stB0 = __builtin_amdgcn_mfma_f32_16x16x32_bf16(ka0, qfB0, stB0, 0, 0, 0);
        stB0 = __builtin_amdgcn_mfma_f32_16x16x32_bf16(ka1, qfB1, stB0, 0, 0, 0);
        stB1 = __builtin_amdgcn_mfma_f32_16x16x32_bf16(ka2, qfB0, stB1, 0, 0, 0);
        stB1 = __builtin_amdgcn_mfma_f32_16x16x32_bf16(ka3, qfB1, stB1, 0, 0, 0);

        const bool more = (s0 + 32 <= smax);
        short8 kn0, kn1, kn2, kn3;
        if (more) {
            long kb0 = ((long)(b * TT + s0 + 32 + fr)) * NQKV + kcol;
            long kb1 = ((long)(b * TT + s0 + 48 + fr)) * NQKV + kcol;
            kn0 = *(const short8*)(qkv + kb0);
            kn1 = *(const short8*)(qkv + kb0 + 32);
            kn2 = *(const short8*)(qkv + kb1);
            kn3 = *(const short8*)(qkv + kb1 + 32);
        }
        short8 vc0 = *(const short8*)(vT + vrow + s0);
        short8 vc1 = *(const short8*)(vT + vrow + 16 * TT + s0);
        short8 vc2 = *(const short8*)(vT + vrow + 32 * TT + s0);
        short8 vc3 = *(const short8*)(vT + vrow + 48 * TT + s0);

        float pA[8];
        float mxA = -3.0e38f;
#pragma unroll
        for (int j = 0; j < 4; ++j) {
            int s = s0 + g * 4 + j;
            float v = stA0[j] * 0.125f;
            v = (s <= t_laneA) ? v : -3.0e38f;
            pA[j] = v; mxA = fmaxf(mxA, v);
        }
#pragma unroll
        for (int j = 0; j < 4; ++j) {
            int s = s0 + 16 + g * 4 + j;
            float v = stA1[j] * 0.125f;
            v = (s <= t_laneA) ? v : -3.0e38f;
            pA[4 + j] = v; mxA = fmaxf(mxA, v);
        }
        mxA = fmaxf(mxA, __shfl_xor(mxA, 16));
        mxA = fmaxf(mxA, __shfl_xor(mxA, 32));
        float mnewA = fmaxf(mA, mxA);
        float corrA = __expf(mA - mnewA);
        float psA = 0.f;
#pragma unroll
        for (int i = 0; i < 8; ++i) {
            float e = __expf(pA[i] - mnewA);
            pA[i] = e; psA += e;
        }
        psA += __shfl_xor(psA, 16);
        psA += __shfl_xor(psA, 32);
        lA = lA * corrA + psA;
        mA = mnewA;

        float pB[8];
        float mxB = -3.0e38f;
#pragma unroll
        for (int j = 0; j < 4; ++j) {
            int s = s0 + g * 4 + j;
            float v = stB0[j] * 0.125f;
            v = (s <= t_laneB) ? v : -3.0e38f;
            pB[j] = v; mxB = fmaxf(mxB, v);
        }
#pragma unroll
        for (int j = 0; j < 4; ++j) {
            int s = s0 + 16 + g * 4 + j;
            float v = stB1[j] * 0.125f;
            v = (s <= t_laneB) ? v : -3.0e38f;
            pB[4 + j] = v; mxB = fmaxf(mxB, v);
        }
        mxB = fmaxf(mxB, __shfl_xor(mxB, 16));
        mxB = fmaxf(mxB, __shfl_xor(mxB, 32));
        float mnewB = fmaxf(mB, mxB);
        float corrB = __expf(mB - mnewB);
        float psB = 0.f;
#pragma unroll
        for (int i = 0; i < 8; ++i) {
            float e = __expf(pB[i] - mnewB);
            pB[i] = e; psB += e;
        }
        psB += __shfl_xor(psB, 16);
        psB += __shfl_xor(psB, 32);
        lB = lB * corrB + psB;
        mB = mnewB;

        unsigned short* P_w = &P_lds[pc][0];
        if (lane < 16) { corr_lds[pc][lane] = corrA; corr_lds[pc][16 + lane] = corrB; }
        {
            unsigned u0 = (unsigned)f2b_bits(pA[0]) | ((unsigned)f2b_bits(pA[1]) << 16);
            unsigned u1 = (unsigned)f2b_bits(pA[2]) | ((unsigned)f2b_bits(pA[3]) << 16);
            unsigned u2 = (unsigned)f2b_bits(pA[4]) | ((unsigned)f2b_bits(pA[5]) << 16);
            unsigned u3 = (unsigned)f2b_bits(pA[6]) | ((unsigned)f2b_bits(pA[7]) << 16);
            *(unsigned*)&P_w[fr * 40 + g * 4]          = u0;
            *(unsigned*)&P_w[fr * 40 + g * 4 + 2]      = u1;
            *(unsigned*)&P_w[fr * 40 + 16 + g * 4]     = u2;
            *(unsigned*)&P_w[fr * 40 + 16 + g * 4 + 2] = u3;
        }
        {
            unsigned u0 = (unsigned)f2b_bits(pB[0]) | ((unsigned)f2b_bits(pB[1]) << 16);
            unsigned u1 = (unsigned)f2b_bits(pB[2]) | ((unsigned)f2b_bits(pB[3]) << 16);
            unsigned u2 = (unsigned)f2b_bits(pB[4]) | ((unsigned)f2b_bits(pB[5]) << 16);
            unsigned u3 = (unsigned)f2b_bits(pB[6]) | ((unsigned)f2b_bits(pB[7]) << 16);
            *(unsigned*)&P_w[(16 + fr) * 40 + g * 4]          = u0;
            *(unsigned*)&P_w[(16 + fr) * 40 + g * 4 + 2]      = u1;
            *(unsigned*)&P_w[(16 + fr) * 40 + 16 + g * 4]     = u2;
            *(unsigned*)&P_w[(16 + fr) * 40 + 16 + g * 4 + 2] = u3;
        }
        __builtin_amdgcn_sched_barrier(0);   // DS writes ordered before reads

        float crA0 = corr_lds[pc][g * 4 + 0], crA1 = corr_lds[pc][g * 4 + 1];
        float crA2 = corr_lds[pc][g * 4 + 2], crA3 = corr_lds[pc][g * 4 + 3];
        float crB0 = corr_lds[pc][16 + g * 4 + 0], crB1 = corr_lds[pc][16 + g * 4 + 1];
        float crB2 = corr_lds[pc][16 + g * 4 + 2], crB3 = corr_lds[pc][16 + g * 4 + 3];
        short8 pfA = *(const short8*)&P_w[fr * 40 + g * 8];
        short8 pfB = *(const short8*)&P_w[(16 + fr) * 40 + g * 8];
#pragma unroll
        for (int dt = 0; dt < 4; ++dt) {
            short8 vc = (dt == 0) ? vc0 : (dt == 1) ? vc1 : (dt == 2) ? vc2 : vc3;
            oaccA[dt][0] *= crA0; oaccA[dt][1] *= crA1;
            oaccA[dt][2] *= crA2; oaccA[dt][3] *= crA3;
            oaccA[dt] = __builtin_amdgcn_mfma_f32_16x16x32_bf16(pfA, vc, oaccA[dt], 0, 0, 0);
            oaccB[dt][0] *= crB0; oaccB[dt][1] *= crB1;
            oaccB[dt][2] *= crB2; oaccB[dt][3] *= crB3;
            oaccB[dt] = __builtin_amdgcn_mfma_f32_16x16x32_bf16(pfB, vc, oaccB[dt], 0, 0, 0);
        }

        if (more) { ka0 = kn0; ka1 = kn1; ka2 = kn2; ka3 = kn3; }
    }

    if (lane < 16) { l_lds[lane] = lA; l_lds[16 + lane] = lB; }
    __builtin_amdgcn_sched_barrier(0);
    float ilA0 = 1.f / l_lds[g * 4 + 0], ilA1 = 1.f / l_lds[g * 4 + 1];
    float ilA2 = 1.f / l_lds[g * 4 + 2], ilA3 = 1.f / l_lds[g * 4 + 3];
    float ilB0 = 1.f / l_lds[16 + g * 4 + 0], ilB1 = 1.f / l_lds[16 + g * 4 + 1];
    float ilB2 = 1.f / l_lds[16 + g * 4 + 2], ilB3 = 1.f / l_lds[16 + g * 4 + 3];
#pragma unroll
    for (int dt = 0; dt < 4; ++dt) {
        long cbaseA = (long)(b * TT + t0) * CC + h * HSZ + dt * 16 + fr;
        long cbaseB = cbaseA + (long)16 * CC;
        o[cbaseA + (g * 4 + 0) * (long)CC] = __float2bfloat16(oaccA[dt][0] * ilA0);
        o[cbaseA + (g * 4 + 1) * (long)CC] = __float2bfloat16(oaccA[dt][1] * ilA1);
        o[cbaseA + (g * 4 + 2) * (long)CC] = __float2bfloat16(oaccA[dt][2] * ilA2);
        o[cbaseA + (g * 4 + 3) * (long)CC] = __float2bfloat16(oaccA[dt][3] * ilA3);
        o[cbaseB + (g * 4 + 0) * (long)CC] = __float2bfloat16(oaccB[dt][0] * ilB0);
        o[cbaseB + (g * 4 + 1) * (long)CC] = __float2bfloat16(oaccB[dt][1] * ilB1);
        o[cbaseB + (g * 4 + 2) * (long)CC] = __float2bfloat16(oaccB[dt][2] * ilB2);
        o[cbaseB + (g * 4 + 3) * (long)CC] = __float2bfloat16(oaccB[dt][3] * ilB3);
    }
}

// ---------------------------------------------------- head on pre-normed bf16 xn
__global__ __launch_bounds__(256) void head_bf(const __hip_bfloat16* __restrict__ xn,
    const float* __restrict__ Wh, const float* __restrict__ bh,
    float* __restrict__ out)
{
    int r = blockIdx.x, tid = threadIdx.x;
    const unsigned short* xr = (const unsigned short*)(xn + (long)r * CC);
    float acc[16];
#pragma unroll
    for (int j = 0; j < 16; ++j) acc[j] = 0.f;
#pragma unroll
    for (int i = 0; i < 3; ++i) {
        int c = tid + i * 256;
        float xnv = b2f(xr[c]);
        const float* wr = Wh + (long)c * 16;
#pragma unroll
        for (int j = 0; j < 16; ++j) acc[j] = fmaf(xnv, wr[j], acc[j]);
    }
#pragma unroll
    for (int off = 32; off > 0; off >>= 1)
#pragma unroll
        for (int j = 0; j < 16; ++j) acc[j] += __shfl_down(acc[j], off);
    __shared__ float red[4][16];
    int w = tid >> 6;
    if ((tid & 63) == 0)
#pragma unroll
        for (int j = 0; j < 16; ++j) red[w][j] = acc[j];
    __syncthreads();
    if (tid < 16)
        out[(long)r * 16 + tid] =
            red[0][tid] + red[1][tid] + red[2][tid] + red[3][tid] + bh[tid];
}

// ---------------------------------------------------------------- launch
extern "C" void kernel_launch(void* const* d_in, const int* in_sizes, int n_in,
                              void* d_out, int out_size, void* d_ws, size_t ws_size,
                              hipStream_t stream)
{
    const int*   idx  = (const int*)  d_in[0];
    const float* tok  = (const float*)d_in[1];
    const float* pos  = (const float*)d_in[2];
    const float* Wq   = (const float*)d_in[3];
    const float* Wk   = (const float*)d_in[4];
    const float* Wv   = (const float*)d_in[5];
    const float* Wo   = (const float*)d_in[6];
    const float* bo   = (const float*)d_in[7];
    const float* W1   = (const float*)d_in[8];
    const float* b1   = (const float*)d_in[9];
    const float* W2   = (const float*)d_in[10];
    const float* b2   = (const float*)d_in[11];
    const float* ln1g = (const float*)d_in[12];
    const float* ln1b = (const float*)d_in[13];
    const float* ln2g = (const float*)d_in[14];
    const float* ln2b = (const float*)d_in[15];
    const float* lnfg = (const float*)d_in[16];
    const float* lnfb = (const float*)d_in[17];
    const float* Wh   = (const float*)d_in[18];
    const float* bh   = (const float*)d_in[19];

    char* w = (char*)d_ws;
    float*          x     = (float*)w;          w += NX * 4;
    __hip_bfloat16* xn_b  = (__hip_bfloat16*)w; w += NX * 2;
    __hip_bfloat16* qkvb  = (__hip_bfloat16*)w; w += (long)BTOT * NQKV * 2;
    __hip_bfloat16* vT    = (__hip_bfloat16*)w; w += NX * 2;
    __hip_bfloat16* o_b   = (__hip_bfloat16*)w; w += NX * 2;
    __hip_bfloat16* hb    = (__hip_bfloat16*)w; w += (long)BTOT * C4 * 2;
    __hip_bfloat16* qkvT  = (__hip_bfloat16*)w; w += (long)LL * NQKV * CC * 2;
    __hip_bfloat16* woT   = (__hip_bfloat16*)w; w += (long)LL * CC * CC * 2;
    __hip_bfloat16* w1T   = (__hip_bfloat16*)w; w += (long)LL * C4 * CC * 2;
    __hip_bfloat16* w2T   = (__hip_bfloat16*)w; w += (long)LL * CC * C4 * 2;
    __hip_bfloat16* pbuf  = (__hip_bfloat16*)w; w += 4 * NX * 2;
    int*            cnt   = (int*)w;            w += 128;

    // zero the 32 slab counters (self-resetting afterwards; capture-safe)
    hipMemsetAsync(cnt, 0, 32 * sizeof(int), stream);

    // ---- all weight conversions upfront (4 launches) ----
    cvt_qkvT<<<dim3(12, 36, LL), 256, 0, stream>>>(Wq, Wk, Wv, qkvT);
    cvtT_k<<<dim3(12, 12, LL), 256, 0, stream>>>(Wo, woT, CC, CC,
        (long)CC * CC, (long)CC * CC);
    cvtT_k<<<dim3(48, 12, LL), 256, 0, stream>>>(W1, w1T, CC, C4,
        (long)CC * C4, (long)CC * C4);
    cvtT_k<<<dim3(12, 48, LL), 256, 0, stream>>>(W2, w2T, C4, CC,
        (long)C4 * CC, (long)C4 * CC);

    // embedding + layer-0 LN1 fused
    embed_ln<<<BTOT, 256, 0, stream>>>(idx, tok, pos, ln1g, ln1b, x, xn_b);

    for (int l = 0; l < LL; ++l) {
        // QKV: M=2048, N=2304, K=768; 576 blocks
        gemm_bf16<1><<<dim3(NQKV / 128, BTOT / 64), 256, 0, stream>>>(
            xn_b, qkvT + (long)l * NQKV * CC, qkvb, nullptr, nullptr, vT,
            nullptr, nullptr, nullptr, CC, CC, CC, NQKV);

        // attention QBLK=32: 768 blocks
        attn_mfma<<<dim3(TT / 32, HH, 4), 64, 0, stream>>>(qkvb, vT, o_b);

        // proj: split-K 4x192 + fused reduce/residual/LN2 -> x, xn
        gemm_bf16<6><<<dim3(CC / 128, BTOT / 64, 4), 256, 0, stream>>>(
            o_b, woT + (long)l * CC * CC, pbuf, x, bo + l * CC, xn_b,
            ln2g + l * CC, ln2b + l * CC, cnt, 192, CC, CC, CC);

        // MLP1: M=2048, N=3072, K=768; 768 blocks (tanh-GELU epilogue)
        gemm_bf16<2><<<dim3(C4 / 128, BTOT / 64), 256, 0, stream>>>(
            xn_b, w1T + (long)l * C4 * CC, hb, nullptr, b1 + l * C4, nullptr,
            nullptr, nullptr, nullptr, CC, CC, CC, C4);

        // MLP2: split-K 4x768 + fused reduce/residual/LN1next (or LNf) -> x, xn
        const float* gN = (l < LL - 1) ? (ln1g + (l + 1) * CC) : lnfg;
        const float* bN = (l < LL - 1) ? (ln1b + (l + 1) * CC) : lnfb;
        gemm_bf16<6><<<dim3(CC / 128, BTOT / 64, 4), 256, 0, stream>>>(
            hb, w2T + (long)l * CC * C4, pbuf, x, b2 + l * CC, xn_b,
            gN, bN, cnt, 768, C4, C4, CC);
    }

    head_bf<<<BTOT, 256, 0, stream>>>(xn_b, Wh, bh, (float*)d_out);
}

// Round 17
// 1363.630 us; speedup vs baseline: 2.2549x; 2.2549x over previous
//
#include <hip/hip_runtime.h>
#include <hip/hip_bf16.h>
#include <math.h>

#define TT   512
#define CC   768
#define HH   12
#define HSZ  64
#define LL   12
#define C4   3072
#define BTOT 2048   // B*T
#define NQKV 2304   // 3*C
#define NX   ((long)BTOT * CC)

typedef __attribute__((ext_vector_type(8))) short short8;
typedef __attribute__((ext_vector_type(4))) float f32x4;

__device__ __forceinline__ unsigned short f2b_bits(float f) {
    unsigned u = __float_as_uint(f);
    return (unsigned short)((u + 0x7fffu + ((u >> 16) & 1u)) >> 16);
}
__device__ __forceinline__ float b2f(unsigned short b) {
    return __uint_as_float((unsigned)b << 16);
}
// tanh-GELU, overflow-safe; |err| vs exact-erf GELU < 3e-3 (below bf16 step)
__device__ __forceinline__ float gelu_t(float v) {
    float u = 0.7978845608f * fmaf(0.044715f * v, v * v, v);
    float th = 1.f - 2.f / (1.f + __expf(2.f * u));
    return 0.5f * v * (1.f + th);
}

// async global->LDS, 16B per lane; LDS dest is wave-uniform base + lane*16B
__device__ __forceinline__ void gl_lds16(const void* g, void* l) {
    __builtin_amdgcn_global_load_lds(
        (const __attribute__((address_space(1))) unsigned int*)g,
        (__attribute__((address_space(3))) unsigned int*)l,
        16, 0, 0);
}

// ------------------------------------------------- embedding + layer-0 LN1
__global__ __launch_bounds__(256) void embed_ln(const int* __restrict__ idx,
    const float* __restrict__ tok, const float* __restrict__ pos,
    const float* __restrict__ g, const float* __restrict__ b,
    float* __restrict__ x, __hip_bfloat16* __restrict__ y)
{
    int r = blockIdx.x, tid = threadIdx.x;
    int t = r & (TT - 1);
    long id = idx[r];
    const float* te = tok + id * (long)CC;
    const float* pe = pos + (long)t * CC;
    float* xr = x + (long)r * CC;
    float v[3];
#pragma unroll
    for (int i = 0; i < 3; ++i) {
        int c = tid + i * 256;
        v[i] = te[c] + pe[c];
        xr[c] = v[i];
    }
    float s  = v[0] + v[1] + v[2];
    float sq = v[0]*v[0] + v[1]*v[1] + v[2]*v[2];
#pragma unroll
    for (int off = 32; off > 0; off >>= 1) {
        s  += __shfl_down(s, off);
        sq += __shfl_down(sq, off);
    }
    __shared__ float ss[4], ssq[4];
    int w = tid >> 6;
    if ((tid & 63) == 0) { ss[w] = s; ssq[w] = sq; }
    __syncthreads();
    s  = ss[0] + ss[1] + ss[2] + ss[3];
    sq = ssq[0] + ssq[1] + ssq[2] + ssq[3];
    float mean = s * (1.0f / CC);
    float var  = sq * (1.0f / CC) - mean * mean;
    float rs   = rsqrtf(var + 1e-5f);
    __hip_bfloat16* yr = y + (long)r * CC;
#pragma unroll
    for (int i = 0; i < 3; ++i) {
        int c = tid + i * 256;
        yr[c] = __float2bfloat16((v[i] - mean) * rs * g[c] + b[c]);
    }
}

// ---------------------------------------- fused split-K reduce + residual + LN
// x[r] += sum of 4 bf16 partial slices + bias; optionally y = LN(x) bf16.
template <bool DOLN>
__global__ __launch_bounds__(256) void red_ln(float* __restrict__ x,
    const unsigned short* __restrict__ p, const float* __restrict__ bias,
    const float* __restrict__ g, const float* __restrict__ b,
    __hip_bfloat16* __restrict__ y)
{
    int r = blockIdx.x, tid = threadIdx.x;
    float* xr = x + (long)r * CC;
    const unsigned short* pr = p + (long)r * CC;
    float v[3];
#pragma unroll
    for (int i = 0; i < 3; ++i) {
        int c = tid + i * 256;
        float s = xr[c] + bias[c];
        s += b2f(pr[c]);
        s += b2f(pr[c + 1 * NX]);
        s += b2f(pr[c + 2 * NX]);
        s += b2f(pr[c + 3 * NX]);
        xr[c] = s;
        v[i] = s;
    }
    if (!DOLN) return;
    float s  = v[0] + v[1] + v[2];
    float sq = v[0]*v[0] + v[1]*v[1] + v[2]*v[2];
#pragma unroll
    for (int off = 32; off > 0; off >>= 1) {
        s  += __shfl_down(s, off);
        sq += __shfl_down(sq, off);
    }
    __shared__ float ss[4], ssq[4];
    int w = tid >> 6;
    if ((tid & 63) == 0) { ss[w] = s; ssq[w] = sq; }
    __syncthreads();
    s  = ss[0] + ss[1] + ss[2] + ss[3];
    sq = ssq[0] + ssq[1] + ssq[2] + ssq[3];
    float mean = s * (1.0f / CC);
    float var  = sq * (1.0f / CC) - mean * mean;
    float rs   = rsqrtf(var + 1e-5f);
    __hip_bfloat16* yr = y + (long)r * CC;
#pragma unroll
    for (int i = 0; i < 3; ++i) {
        int c = tid + i * 256;
        yr[c] = __float2bfloat16((v[i] - mean) * rs * g[c] + b[c]);
    }
}

// ------------------------------------------------- weight convert/transpose
// src fp32 [R][D] -> dst bf16 [D][R]; 64x64 tiles; grid (D/64, R/64, L)
__global__ __launch_bounds__(256) void cvtT_k(const float* __restrict__ src,
    __hip_bfloat16* __restrict__ dst, int R, int D, long sSrc, long sDst)
{
    src += (long)blockIdx.z * sSrc;
    dst += (long)blockIdx.z * sDst;
    __shared__ float t[64][65];
    int d0 = blockIdx.x * 64, r0 = blockIdx.y * 64;
    int tid = threadIdx.x;
#pragma unroll
    for (int i = 0; i < 4; ++i) {
        int flat = tid + i * 256;
        int r = flat >> 4, c4 = (flat & 15) * 4;
        float4 v = *(const float4*)&src[(long)(r0 + r) * D + d0 + c4];
        t[r][c4 + 0] = v.x; t[r][c4 + 1] = v.y;
        t[r][c4 + 2] = v.z; t[r][c4 + 3] = v.w;
    }
    __syncthreads();
#pragma unroll
    for (int i = 0; i < 4; ++i) {
        int flat = tid + i * 256;
        int n = flat >> 4, kq = (flat & 15) * 4;
        ushort4 o;
        o.x = f2b_bits(t[kq + 0][n]); o.y = f2b_bits(t[kq + 1][n]);
        o.z = f2b_bits(t[kq + 2][n]); o.w = f2b_bits(t[kq + 3][n]);
        *(ushort4*)&dst[(long)(d0 + n) * R + r0 + kq] = o;
    }
}

// merged W1 [L][768][3072] and W2 [L][3072][768] converts; grid (48, 12, 2L).
// z < L: W1 tile (d0 = bx, r0 = by); z >= L: W2 tile (d0 = by, r0 = bx).
__global__ __launch_bounds__(256) void cvtT_mlp(const float* __restrict__ W1,
    const float* __restrict__ W2, __hip_bfloat16* __restrict__ w1T,
    __hip_bfloat16* __restrict__ w2T)
{
    int z = blockIdx.z;
    const bool is2 = (z >= LL);
    int l = is2 ? z - LL : z;
    const float* src = (is2 ? W2 : W1) + (long)l * CC * C4;
    __hip_bfloat16* dst = (is2 ? w2T : w1T) + (long)l * CC * C4;
    const int R = is2 ? C4 : CC;           // src rows
    const int D = is2 ? CC : C4;           // src cols
    int d0 = (is2 ? blockIdx.y : blockIdx.x) * 64;
    int r0 = (is2 ? blockIdx.x : blockIdx.y) * 64;

    __shared__ float t[64][65];
    int tid = threadIdx.x;
#pragma unroll
    for (int i = 0; i < 4; ++i) {
        int flat = tid + i * 256;
        int r = flat >> 4, c4 = (flat & 15) * 4;
        float4 v = *(const float4*)&src[(long)(r0 + r) * D + d0 + c4];
        t[r][c4 + 0] = v.x; t[r][c4 + 1] = v.y;
        t[r][c4 + 2] = v.z; t[r][c4 + 3] = v.w;
    }
    __syncthreads();
#pragma unroll
    for (int i = 0; i < 4; ++i) {
        int flat = tid + i * 256;
        int n = flat >> 4, kq = (flat & 15) * 4;
        ushort4 o;
        o.x = f2b_bits(t[kq + 0][n]); o.y = f2b_bits(t[kq + 1][n]);
        o.z = f2b_bits(t[kq + 2][n]); o.w = f2b_bits(t[kq + 3][n]);
        *(ushort4*)&dst[(long)(d0 + n) * R + r0 + kq] = o;
    }
}

// Wq/Wk/Wv [L][h][768][64] -> qkvT_all [L][2304][768]; grid (12, 36, L)
__global__ __launch_bounds__(256) void cvt_qkvT(const float* __restrict__ Wq,
    const float* __restrict__ Wk, const float* __restrict__ Wv,
    __hip_bfloat16* __restrict__ out)
{
    int c0 = blockIdx.x * 64;
    int g  = blockIdx.y;
    int l  = blockIdx.z;
    int which = g / 12, h = g % 12;
    const long wAtt = (long)HH * CC * HSZ;
    const float* src = (which == 0 ? Wq : which == 1 ? Wk : Wv)
                       + l * wAtt + (long)h * CC * HSZ;   // [768][64]
    __hip_bfloat16* dst = out + (long)l * NQKV * CC + (long)(which * CC + h * HSZ) * CC;
    __shared__ float t[64][65];
    int tid = threadIdx.x;
#pragma unroll
    for (int i = 0; i < 4; ++i) {
        int flat = tid + i * 256;
        int r = flat >> 4, c4 = (flat & 15) * 4;
        float4 v = *(const float4*)&src[(long)(c0 + r) * HSZ + c4];
        t[r][c4 + 0] = v.x; t[r][c4 + 1] = v.y;
        t[r][c4 + 2] = v.z; t[r][c4 + 3] = v.w;
    }
    __syncthreads();
#pragma unroll
    for (int i = 0; i < 4; ++i) {
        int flat = tid + i * 256;
        int n = flat >> 4, kq = (flat & 15) * 4;
        ushort4 o;
        o.x = f2b_bits(t[kq + 0][n]); o.y = f2b_bits(t[kq + 1][n]);
        o.z = f2b_bits(t[kq + 2][n]); o.w = f2b_bits(t[kq + 3][n]);
        *(ushort4*)&dst[(long)n * CC + c0 + kq] = o;
    }
}

// ---------------------------------------------------------------- bf16 MFMA GEMM (64x128)
// Depth-4 pipeline, counted vmcnt, T1 XCD swizzle, T2 bank rotation.
// EPI 1: QKV (cols<1536 -> Cb, cols>=1536 -> Vt transposed);
// EPI 2: +bias tanh-GELU -> bf16;
// EPI 5: split-K over blockIdx.z: store bf16 partial to Cb + sk*NX (no bias).
template <int EPI>
__global__ __launch_bounds__(256, 3) void gemm_bf16(
    const __hip_bfloat16* __restrict__ A,
    const __hip_bfloat16* __restrict__ BT,
    __hip_bfloat16* __restrict__ Cb, float* __restrict__ Cf,
    const float* __restrict__ bias, __hip_bfloat16* __restrict__ Vt,
    int K, int lda, int ldb, int ldc)
{
    __shared__ short Asm[4][64 * 32];
    __shared__ short Bsm[4][128 * 32];
    const int tid  = threadIdx.x;
    const int lane = tid & 63;
    const int wid  = tid >> 6;
    const int wm = wid >> 1, wn = wid & 1;

    const int gx = gridDim.x;
    const int slice = gx * gridDim.y;            // divisible by 8
    int flat = blockIdx.y * gx + blockIdx.x;
    int swz  = (flat & 7) * (slice >> 3) + (flat >> 3);
    const int row0 = (swz / gx) * 64, col0 = (swz % gx) * 128;
    const int sk = (EPI == 5) ? blockIdx.z : 0;

    const int gr = tid >> 2;               // staging row 0..63
    const int cb = ((tid & 3) + (tid >> 3)) & 3;   // T2 source rotation
    const int gk = cb * 8;                 // k offset in shorts
    const __hip_bfloat16* Ap = A  + (long)(row0 + gr) * lda + sk * K + gk;
    const __hip_bfloat16* Bp = BT + (long)(col0 + gr) * ldb + sk * K + gk;
    const int lofs = wid * 512;            // per-wave LDS segment (shorts)

    f32x4 acc[2][4] = {};
    const int fr = lane & 15, g = lane >> 4;

    int offA[2], offB[4];
#pragma unroll
    for (int m = 0; m < 2; ++m) {
        int row = wm * 32 + m * 16 + fr;
        offA[m] = row * 32 + (((g - (row >> 1)) & 3) * 8);
    }
#pragma unroll
    for (int n = 0; n < 4; ++n) {
        int row = wn * 64 + n * 16 + fr;
        offB[n] = row * 32 + (((g - (row >> 1)) & 3) * 8);
    }

#define STAGE(buf)                                                          \
    do {                                                                    \
        gl_lds16(Ap, &Asm[buf][lofs]);                                      \
        gl_lds16(Bp, &Bsm[buf][lofs]);                                      \
        gl_lds16(Bp + (long)64 * ldb, &Bsm[buf][lofs + 64 * 32]);           \
        Ap += 32; Bp += 32;                                                 \
    } while (0)

    STAGE(0); STAGE(1); STAGE(2);

    const int nt = K >> 5;                 // >= 3
    for (int t = 0; t < nt; ++t) {
        if (t < nt - 2)       asm volatile("s_waitcnt vmcnt(6)" ::: "memory");
        else if (t == nt - 2) asm volatile("s_waitcnt vmcnt(3)" ::: "memory");
        else                  asm volatile("s_waitcnt vmcnt(0)" ::: "memory");
        __builtin_amdgcn_s_barrier();
        __builtin_amdgcn_sched_barrier(0);
        if (t + 3 < nt) STAGE((t + 3) & 3);

        const int cur = t & 3;
        short8 af[2], bf[4];
#pragma unroll
        for (int m = 0; m < 2; ++m)
            af[m] = *(const short8*)&Asm[cur][offA[m]];
#pragma unroll
        for (int n = 0; n < 4; ++n)
            bf[n] = *(const short8*)&Bsm[cur][offB[n]];
#pragma unroll
        for (int m = 0; m < 2; ++m)
#pragma unroll
            for (int n = 0; n < 4; ++n)
                acc[m][n] = __builtin_amdgcn_mfma_f32_16x16x32_bf16(
                    af[m], bf[n], acc[m][n], 0, 0, 0);
    }
#undef STAGE

    const int fq = lane >> 4;
#pragma unroll
    for (int m = 0; m < 2; ++m) {
        int rbase = row0 + wm * 32 + m * 16 + fq * 4;
#pragma unroll
        for (int n = 0; n < 4; ++n) {
            int col = col0 + wn * 64 + n * 16 + fr;
            if (EPI == 1 && col >= 1536) {
                int hd = col - 1536;
                int b = rbase >> 9, t = rbase & (TT - 1);
                ushort4 o;
                o.x = f2b_bits(acc[m][n][0]); o.y = f2b_bits(acc[m][n][1]);
                o.z = f2b_bits(acc[m][n][2]); o.w = f2b_bits(acc[m][n][3]);
                *(ushort4*)&Vt[((long)(b * HH + (hd >> 6)) * HSZ + (hd & 63)) * TT + t] = o;
                continue;
            }
            float bv = (EPI == 2) ? bias[col] : 0.f;
#pragma unroll
            for (int j = 0; j < 4; ++j) {
                long row = rbase + j;
                float v = acc[m][n][j];
                if (EPI == 1) {
                    Cb[row * ldc + col] = __float2bfloat16(v);
                } else if (EPI == 2) {
                    Cb[row * ldc + col] = __float2bfloat16(gelu_t(v + bv));
                } else { // EPI == 5: bf16 partial
                    Cb[(long)sk * NX + row * ldc + col] = __float2bfloat16(v);
                }
            }
        }
    }
}

// ---------------------------------------------------------------- MFMA flash attention
// QBLK=32: one wave handles 32 queries (halves A/B), sharing K-register chunks
// and V loads. One wave per block, NO __syncthreads. P/corr double-buffered by
// chunk parity. T1 XCD swizzle (768 blocks).
__global__ __launch_bounds__(64) void attn_mfma(
    const __hip_bfloat16* __restrict__ qkv,
    const __hip_bfloat16* __restrict__ vT,
    __hip_bfloat16* __restrict__ o)
{
    int flat = blockIdx.x + 16 * (blockIdx.y + 12 * blockIdx.z);
    int swz  = (flat & 7) * 96 + (flat >> 3);      // 768 blocks, 8 XCDs
    const int qt = swz & 15;
    const int h  = (swz >> 4) % 12;
    const int b  = swz / 192;
    const int lane = threadIdx.x;
    const int t0 = qt * 32;
    const int fr = lane & 15, g = lane >> 4;

    __shared__ unsigned short P_lds[2][32 * 40];
    __shared__ float corr_lds[2][32], l_lds[32];

    const long qbaseA = ((long)(b * TT + t0 + fr)) * NQKV + h * HSZ + g * 8;
    const long qbaseB = qbaseA + (long)16 * NQKV;
    short8 qfA0 = *(const short8*)(qkv + qbaseA);
    short8 qfA1 = *(const short8*)(qkv + qbaseA + 32);
    short8 qfB0 = *(const short8*)(qkv + qbaseB);
    short8 qfB1 = *(const short8*)(qkv + qbaseB + 32);

    f32x4 oaccA[4] = {}, oaccB[4] = {};
    float mA = -3.0e38f, lA = 0.f, mB = -3.0e38f, lB = 0.f;
    const int t_laneA = t0 + fr;
    const int t_laneB = t0 + 16 + fr;
    const int smax = t0 + 31;
    const long kcol = CC + h * HSZ + g * 8;
    const long vrow = (((long)(b * HH + h) * HSZ) + fr) * TT + g * 8;

    short8 ka0, ka1, ka2, ka3;
    {
        long kb0 = ((long)(b * TT + fr)) * NQKV + kcol;
        long kb1 = ((long)(b * TT + 16 + fr)) * NQKV + kcol;
        ka0 = *(const short8*)(qkv + kb0);
        ka1 = *(const short8*)(qkv + kb0 + 32);
        ka2 = *(const short8*)(qkv + kb1);
        ka3 = *(const short8*)(qkv + kb1 + 32);
    }

    for (int s0 = 0; s0 <= smax; s0 += 32) {
        const int pc = (s0 >> 5) & 1;
        f32x4 stA0 = {}, stA1 = {}, stB0 = {}, stB1 = {};
        stA0 = __builtin_amdgcn_mfma_f32_16x16x32_bf16(ka0, qfA0, stA0, 0, 0, 0);
        stA0 = __builtin_amdgcn_mfma_f32_16x16x32_bf16(ka1, qfA1, stA0, 0, 0, 0);
        stA1 = __builtin_amdgcn_mfma_f32_16x16x32_bf16(ka2, qfA0, stA1, 0, 0, 0);
        stA1 = __builtin_amdgcn_mfma_f32_16x16x32_bf16(ka3, qfA1, stA1, 0, 0, 0);
        stB0 = __builtin_amdgcn_mfma_f32_16x16x32_bf16(ka0, qfB0, stB0, 0, 0, 0);
        stB0 = __builtin_amdgcn_mfma_f32_16x16x32_bf16(ka1, qfB1, stB0, 0, 0, 0);
        stB1 = __builtin_amdgcn_mfma_f32_16x16x32_bf16(ka2, qfB0, stB1, 0, 0, 0);
        stB1 = __builtin_amdgcn_mfma_f32_16x16x32_bf16(ka3, qfB1, stB1, 0, 0, 0);

        const bool more = (s0 + 32 <= smax);
        short8 kn0, kn1, kn2, kn3;
        if (more) {
            long kb0 = ((long)(b * TT + s0 + 32 + fr)) * NQKV + kcol;
            long kb1 = ((long)(b * TT + s0 + 48 + fr)) * NQKV + kcol;
            kn0 = *(const short8*)(qkv + kb0);
            kn1 = *(const short8*)(qkv + kb0 + 32);
            kn2 = *(const short8*)(qkv + kb1);
            kn3 = *(const short8*)(qkv + kb1 + 32);
        }
        short8 vc0 = *(const short8*)(vT + vrow + s0);
        short8 vc1 = *(const short8*)(vT + vrow + 16 * TT + s0);
        short8 vc2 = *(const short8*)(vT + vrow + 32 * TT + s0);
        short8 vc3 = *(const short8*)(vT + vrow + 48 * TT + s0);

        float pA[8];
        float mxA = -3.0e38f;
#pragma unroll
        for (int j = 0; j < 4; ++j) {
            int s = s0 + g * 4 + j;
            float v = stA0[j] * 0.125f;
            v = (s <= t_laneA) ? v : -3.0e38f;
            pA[j] = v; mxA = fmaxf(mxA, v);
        }
#pragma unroll
        for (int j = 0; j < 4; ++j) {
            int s = s0 + 16 + g * 4 + j;
            float v = stA1[j] * 0.125f;
            v = (s <= t_laneA) ? v : -3.0e38f;
            pA[4 + j] = v; mxA = fmaxf(mxA, v);
        }
        mxA = fmaxf(mxA, __shfl_xor(mxA, 16));
        mxA = fmaxf(mxA, __shfl_xor(mxA, 32));
        float mnewA = fmaxf(mA, mxA);
        float corrA = __expf(mA - mnewA);
        float psA = 0.f;
#pragma unroll
        for (int i = 0; i < 8; ++i) {
            float e = __expf(pA[i] - mnewA);
            pA[i] = e; psA += e;
        }
        psA += __shfl_xor(psA, 16);
        psA += __shfl_xor(psA, 32);
        lA = lA * corrA + psA;
        mA = mnewA;

        float pB[8];
        float mxB = -3.0e38f;
#pragma unroll
        for (int j = 0; j < 4; ++j) {
            int s = s0 + g * 4 + j;
            float v = stB0[j] * 0.125f;
            v = (s <= t_laneB) ? v : -3.0e38f;
            pB[j] = v; mxB = fmaxf(mxB, v);
        }
#pragma unroll
        for (int j = 0; j < 4; ++j) {
            int s = s0 + 16 + g * 4 + j;
            float v = stB1[j] * 0.125f;
            v = (s <= t_laneB) ? v : -3.0e38f;
            pB[4 + j] = v; mxB = fmaxf(mxB, v);
        }
        mxB = fmaxf(mxB, __shfl_xor(mxB, 16));
        mxB = fmaxf(mxB, __shfl_xor(mxB, 32));
        float mnewB = fmaxf(mB, mxB);
        float corrB = __expf(mB - mnewB);
        float psB = 0.f;
#pragma unroll
        for (int i = 0; i < 8; ++i) {
            float e = __expf(pB[i] - mnewB);
            pB[i] = e; psB += e;
        }
        psB += __shfl_xor(psB, 16);
        psB += __shfl_xor(psB, 32);
        lB = lB * corrB + psB;
        mB = mnewB;

        unsigned short* P_w = &P_lds[pc][0];
        if (lane < 16) { corr_lds[pc][lane] = corrA; corr_lds[pc][16 + lane] = corrB; }
        {
            unsigned u0 = (unsigned)f2b_bits(pA[0]) | ((unsigned)f2b_bits(pA[1]) << 16);
            unsigned u1 = (unsigned)f2b_bits(pA[2]) | ((unsigned)f2b_bits(pA[3]) << 16);
            unsigned u2 = (unsigned)f2b_bits(pA[4]) | ((unsigned)f2b_bits(pA[5]) << 16);
            unsigned u3 = (unsigned)f2b_bits(pA[6]) | ((unsigned)f2b_bits(pA[7]) << 16);
            *(unsigned*)&P_w[fr * 40 + g * 4]          = u0;
            *(unsigned*)&P_w[fr * 40 + g * 4 + 2]      = u1;
            *(unsigned*)&P_w[fr * 40 + 16 + g * 4]     = u2;
            *(unsigned*)&P_w[fr * 40 + 16 + g * 4 + 2] = u3;
        }
        {
            unsigned u0 = (unsigned)f2b_bits(pB[0]) | ((unsigned)f2b_bits(pB[1]) << 16);
            unsigned u1 = (unsigned)f2b_bits(pB[2]) | ((unsigned)f2b_bits(pB[3]) << 16);
            unsigned u2 = (unsigned)f2b_bits(pB[4]) | ((unsigned)f2b_bits(pB[5]) << 16);
            unsigned u3 = (unsigned)f2b_bits(pB[6]) | ((unsigned)f2b_bits(pB[7]) << 16);
            *(unsigned*)&P_w[(16 + fr) * 40 + g * 4]          = u0;
            *(unsigned*)&P_w[(16 + fr) * 40 + g * 4 + 2]      = u1;
            *(unsigned*)&P_w[(16 + fr) * 40 + 16 + g * 4]     = u2;
            *(unsigned*)&P_w[(16 + fr) * 40 + 16 + g * 4 + 2] = u3;
        }
        __builtin_amdgcn_sched_barrier(0);   // DS writes ordered before reads

        float crA0 = corr_lds[pc][g * 4 + 0], crA1 = corr_lds[pc][g * 4 + 1];
        float crA2 = corr_lds[pc][g * 4 + 2], crA3 = corr_lds[pc][g * 4 + 3];
        float crB0 = corr_lds[pc][16 + g * 4 + 0], crB1 = corr_lds[pc][16 + g * 4 + 1];
        float crB2 = corr_lds[pc][16 + g * 4 + 2], crB3 = corr_lds[pc][16 + g * 4 + 3];
        short8 pfA = *(const short8*)&P_w[fr * 40 + g * 8];
        short8 pfB = *(const short8*)&P_w[(16 + fr) * 40 + g * 8];
#pragma unroll
        for (int dt = 0; dt < 4; ++dt) {
            short8 vc = (dt == 0) ? vc0 : (dt == 1) ? vc1 : (dt == 2) ? vc2 : vc3;
            oaccA[dt][0] *= crA0; oaccA[dt][1] *= crA1;
            oaccA[dt][2] *= crA2; oaccA[dt][3] *= crA3;
            oaccA[dt] = __builtin_amdgcn_mfma_f32_16x16x32_bf16(pfA, vc, oaccA[dt], 0, 0, 0);
            oaccB[dt][0] *= crB0; oaccB[dt][1] *= crB1;
            oaccB[dt][2] *= crB2; oaccB[dt][3] *= crB3;
            oaccB[dt] = __builtin_amdgcn_mfma_f32_16x16x32_bf16(pfB, vc, oaccB[dt], 0, 0, 0);
        }

        if (more) { ka0 = kn0; ka1 = kn1; ka2 = kn2; ka3 = kn3; }
    }

    if (lane < 16) { l_lds[lane] = lA; l_lds[16 + lane] = lB; }
    __builtin_amdgcn_sched_barrier(0);
    float ilA0 = 1.f / l_lds[g * 4 + 0], ilA1 = 1.f / l_lds[g * 4 + 1];
    float ilA2 = 1.f / l_lds[g * 4 + 2], ilA3 = 1.f / l_lds[g * 4 + 3];
    float ilB0 = 1.f / l_lds[16 + g * 4 + 0], ilB1 = 1.f / l_lds[16 + g * 4 + 1];
    float ilB2 = 1.f / l_lds[16 + g * 4 + 2], ilB3 = 1.f / l_lds[16 + g * 4 + 3];
#pragma unroll
    for (int dt = 0; dt < 4; ++dt) {
        long cbaseA = (long)(b * TT + t0) * CC + h * HSZ + dt * 16 + fr;
        long cbaseB = cbaseA + (long)16 * CC;
        o[cbaseA + (g * 4 + 0) * (long)CC] = __float2bfloat16(oaccA[dt][0] * ilA0);
        o[cbaseA + (g * 4 + 1) * (long)CC] = __float2bfloat16(oaccA[dt][1] * ilA1);
        o[cbaseA + (g * 4 + 2) * (long)CC] = __float2bfloat16(oaccA[dt][2] * ilA2);
        o[cbaseA + (g * 4 + 3) * (long)CC] = __float2bfloat16(oaccA[dt][3] * ilA3);
        o[cbaseB + (g * 4 + 0) * (long)CC] = __float2bfloat16(oaccB[dt][0] * ilB0);
        o[cbaseB + (g * 4 + 1) * (long)CC] = __float2bfloat16(oaccB[dt][1] * ilB1);
        o[cbaseB + (g * 4 + 2) * (long)CC] = __float2bfloat16(oaccB[dt][2] * ilB2);
        o[cbaseB + (g * 4 + 3) * (long)CC] = __float2bfloat16(oaccB[dt][3] * ilB3);
    }
}

// ---------------------------------------------------- head on pre-normed bf16 xn
__global__ __launch_bounds__(256) void head_bf(const __hip_bfloat16* __restrict__ xn,
    const float* __restrict__ Wh, const float* __restrict__ bh,
    float* __restrict__ out)
{
    int r = blockIdx.x, tid = threadIdx.x;
    const unsigned short* xr = (const unsigned short*)(xn + (long)r * CC);
    float acc[16];
#pragma unroll
    for (int j = 0; j < 16; ++j) acc[j] = 0.f;
#pragma unroll
    for (int i = 0; i < 3; ++i) {
        int c = tid + i * 256;
        float xnv = b2f(xr[c]);
        const float* wr = Wh + (long)c * 16;
#pragma unroll
        for (int j = 0; j < 16; ++j) acc[j] = fmaf(xnv, wr[j], acc[j]);
    }
#pragma unroll
    for (int off = 32; off > 0; off >>= 1)
#pragma unroll
        for (int j = 0; j < 16; ++j) acc[j] += __shfl_down(acc[j], off);
    __shared__ float red[4][16];
    int w = tid >> 6;
    if ((tid & 63) == 0)
#pragma unroll
        for (int j = 0; j < 16; ++j) red[w][j] = acc[j];
    __syncthreads();
    if (tid < 16)
        out[(long)r * 16 + tid] =
            red[0][tid] + red[1][tid] + red[2][tid] + red[3][tid] + bh[tid];
}

// ---------------------------------------------------------------- launch
extern "C" void kernel_launch(void* const* d_in, const int* in_sizes, int n_in,
                              void* d_out, int out_size, void* d_ws, size_t ws_size,
                              hipStream_t stream)
{
    const int*   idx  = (const int*)  d_in[0];
    const float* tok  = (const float*)d_in[1];
    const float* pos  = (const float*)d_in[2];
    const float* Wq   = (const float*)d_in[3];
    const float* Wk   = (const float*)d_in[4];
    const float* Wv   = (const float*)d_in[5];
    const float* Wo   = (const float*)d_in[6];
    const float* bo   = (const float*)d_in[7];
    const float* W1   = (const float*)d_in[8];
    const float* b1   = (const float*)d_in[9];
    const float* W2   = (const float*)d_in[10];
    const float* b2   = (const float*)d_in[11];
    const float* ln1g = (const float*)d_in[12];
    const float* ln1b = (const float*)d_in[13];
    const float* ln2g = (const float*)d_in[14];
    const float* ln2b = (const float*)d_in[15];
    const float* lnfg = (const float*)d_in[16];
    const float* lnfb = (const float*)d_in[17];
    const float* Wh   = (const float*)d_in[18];
    const float* bh   = (const float*)d_in[19];

    char* w = (char*)d_ws;
    float*          x     = (float*)w;          w += NX * 4;
    __hip_bfloat16* xn_b  = (__hip_bfloat16*)w; w += NX * 2;
    __hip_bfloat16* qkvb  = (__hip_bfloat16*)w; w += (long)BTOT * NQKV * 2;
    __hip_bfloat16* vT    = (__hip_bfloat16*)w; w += NX * 2;
    __hip_bfloat16* o_b   = (__hip_bfloat16*)w; w += NX * 2;
    __hip_bfloat16* hb    = (__hip_bfloat16*)w; w += (long)BTOT * C4 * 2;
    __hip_bfloat16* qkvT  = (__hip_bfloat16*)w; w += (long)LL * NQKV * CC * 2;
    __hip_bfloat16* woT   = (__hip_bfloat16*)w; w += (long)LL * CC * CC * 2;
    __hip_bfloat16* w1T   = (__hip_bfloat16*)w; w += (long)LL * C4 * CC * 2;
    __hip_bfloat16* w2T   = (__hip_bfloat16*)w; w += (long)LL * CC * C4 * 2;
    __hip_bfloat16* pbuf  = (__hip_bfloat16*)w; w += 4 * NX * 2;

    // ---- all weight conversions upfront (3 launches) ----
    cvt_qkvT<<<dim3(12, 36, LL), 256, 0, stream>>>(Wq, Wk, Wv, qkvT);
    cvtT_k<<<dim3(12, 12, LL), 256, 0, stream>>>(Wo, woT, CC, CC,
        (long)CC * CC, (long)CC * CC);
    cvtT_mlp<<<dim3(48, 12, 2 * LL), 256, 0, stream>>>(W1, W2, w1T, w2T);

    // embedding + layer-0 LN1 fused
    embed_ln<<<BTOT, 256, 0, stream>>>(idx, tok, pos, ln1g, ln1b, x, xn_b);

    for (int l = 0; l < LL; ++l) {
        // QKV: M=2048, N=2304, K=768; 576 blocks
        gemm_bf16<1><<<dim3(NQKV / 128, BTOT / 64), 256, 0, stream>>>(
            xn_b, qkvT + (long)l * NQKV * CC, qkvb, nullptr, nullptr, vT,
            CC, CC, CC, NQKV);

        // attention QBLK=32: 768 blocks
        attn_mfma<<<dim3(TT / 32, HH, 4), 64, 0, stream>>>(qkvb, vT, o_b);

        // proj: M=2048, N=768, K=768 split 4x192 -> bf16 partials; 768 blocks
        gemm_bf16<5><<<dim3(CC / 128, BTOT / 64, 4), 256, 0, stream>>>(
            o_b, woT + (long)l * CC * CC, pbuf, nullptr, nullptr, nullptr,
            192, CC, CC, CC);

        // x += sum(partials) + bo; xn = LN2(x)
        red_ln<true><<<BTOT, 256, 0, stream>>>(x, (const unsigned short*)pbuf,
            bo + l * CC, ln2g + l * CC, ln2b + l * CC, xn_b);

        // MLP1: M=2048, N=3072, K=768; 768 blocks (tanh-GELU epilogue)
        gemm_bf16<2><<<dim3(C4 / 128, BTOT / 64), 256, 0, stream>>>(
            xn_b, w1T + (long)l * C4 * CC, hb, nullptr, b1 + l * C4, nullptr,
            CC, CC, CC, C4);

        // MLP2: M=2048, N=768, K=3072 split 4x768 -> bf16 partials; 768 blocks
        gemm_bf16<5><<<dim3(CC / 128, BTOT / 64, 4), 256, 0, stream>>>(
            hb, w2T + (long)l * CC * C4, pbuf, nullptr, nullptr, nullptr,
            768, C4, C4, CC);

        // x += sum(partials) + b2; xn = LN1(next) or LNf (last layer)
        const float* gN = (l < LL - 1) ? (ln1g + (l + 1) * CC) : lnfg;
        const float* bN = (l < LL - 1) ? (ln1b + (l + 1) * CC) : lnfb;
        red_ln<true><<<BTOT, 256, 0, stream>>>(x, (const unsigned short*)pbuf,
            b2 + l * CC, gN, bN, xn_b);
    }

    head_bf<<<BTOT, 256, 0, stream>>>(xn_b, Wh, bh, (float*)d_out);
}